// Round 1
// baseline (867.429 us; speedup 1.0000x reference)
//
#include <hip/hip_runtime.h>

#define NQ 2048
#define NT 131072
#define DD 64
#define MM 1024

// Yq = Xq @ W for both weight matrices. One block per row, 64 threads = cols.
__global__ void yq_kernel(const float* __restrict__ Xq,
                          const float* __restrict__ Wa,
                          const float* __restrict__ Wb,
                          float* __restrict__ Yqa,
                          float* __restrict__ Yqb) {
    int r = blockIdx.x;
    int j = threadIdx.x;
    float sa = 0.f, sb = 0.f;
#pragma unroll
    for (int k = 0; k < DD; ++k) {
        float x = Xq[r * DD + k];
        sa = fmaf(x, Wa[k * DD + j], sa);
        sb = fmaf(x, Wb[k * DD + j], sb);
    }
    Yqa[r * DD + j] = sa;
    Yqb[r * DD + j] = sb;
}

// Pass A: one wave per edge. Compute alpha=ELU(yqa·xt+ba), beta=sigmoid(yqb·xt+bb).
// Store a=exp(alpha), beta; accumulate s[v] += a.
__global__ void edgeA_kernel(const float* __restrict__ Yqa,
                             const float* __restrict__ Yqb,
                             const float* __restrict__ Xt,
                             const float* __restrict__ ba,
                             const float* __restrict__ bb,
                             const int* __restrict__ u_idx,
                             const int* __restrict__ v_idx,
                             float* __restrict__ a_out,
                             float* __restrict__ beta_out,
                             float* __restrict__ s,
                             int E) {
    int gtid = blockIdx.x * blockDim.x + threadIdx.x;
    int lane = gtid & 63;
    int wid = gtid >> 6;
    int nw = (gridDim.x * blockDim.x) >> 6;
    for (int e = wid; e < E; e += nw) {
        int u = u_idx[e];
        int v = v_idx[e];
        float xt = Xt[v * DD + lane];
        float pa = Yqa[u * DD + lane] * xt;
        float pb = Yqb[u * DD + lane] * xt;
#pragma unroll
        for (int off = 32; off > 0; off >>= 1) {
            pa += __shfl_xor(pa, off);
            pb += __shfl_xor(pb, off);
        }
        if (lane == 0) {
            float la = pa + ba[0];
            float alpha = la > 0.f ? la : expm1f(la);   // ELU
            float a = expf(alpha);
            float beta = 1.f / (1.f + expf(-(pb + bb[0])));
            a_out[e] = a;
            beta_out[e] = beta;
            atomicAdd(&s[v], a);
        }
    }
}

// Initialize output Xt rows: rows with candidates -> 0 (acc base), else passthrough Xt.
__global__ void init_rows_kernel(const float* __restrict__ Xt,
                                 const float* __restrict__ s,
                                 float* __restrict__ outXt) {
    int idx = blockIdx.x * blockDim.x + threadIdx.x;   // over NT*DD
    int v = idx >> 6;
    outXt[idx] = (s[v] > 0.f) ? 0.f : Xt[idx];
}

// Consensus overwrite: outXt[vc[i]] = Xq[uc[i]]  (these rows have deg==0).
__global__ void consensus_kernel(const float* __restrict__ Xq,
                                 const int* __restrict__ uc,
                                 const int* __restrict__ vc,
                                 float* __restrict__ outXt) {
    int idx = blockIdx.x * blockDim.x + threadIdx.x;   // over MM*DD
    int i = idx >> 6;
    int d = idx & 63;
    outXt[vc[i] * DD + d] = Xq[uc[i] * DD + d];
}

// Pass B: one wave per edge. w = a/s[v] + 1e-10; h = (1-beta)*xq + beta*xt;
// atomicAdd into outXt row (64 coalesced lane atomics).
__global__ void edgeB_kernel(const float* __restrict__ Xq,
                             const float* __restrict__ Xt,
                             const int* __restrict__ u_idx,
                             const int* __restrict__ v_idx,
                             const float* __restrict__ a_in,
                             const float* __restrict__ beta_in,
                             const float* __restrict__ s,
                             float* __restrict__ outXt,
                             int E) {
    int gtid = blockIdx.x * blockDim.x + threadIdx.x;
    int lane = gtid & 63;
    int wid = gtid >> 6;
    int nw = (gridDim.x * blockDim.x) >> 6;
    for (int e = wid; e < E; e += nw) {
        int u = u_idx[e];
        int v = v_idx[e];
        float w = a_in[e] / s[v] + 1e-10f;
        float beta = beta_in[e];
        float h = (1.f - beta) * Xq[u * DD + lane] + beta * Xt[v * DD + lane];
        atomicAdd(&outXt[v * DD + lane], w * h);
    }
}

extern "C" void kernel_launch(void* const* d_in, const int* in_sizes, int n_in,
                              void* d_out, int out_size, void* d_ws, size_t ws_size,
                              hipStream_t stream) {
    const float* Xq = (const float*)d_in[0];
    const float* Xt = (const float*)d_in[1];
    const float* Wa = (const float*)d_in[2];
    const float* ba = (const float*)d_in[3];
    const float* Wb = (const float*)d_in[4];
    const float* bb = (const float*)d_in[5];
    const int* u_idx = (const int*)d_in[6];
    const int* v_idx = (const int*)d_in[7];
    const int* uc = (const int*)d_in[8];
    const int* vc = (const int*)d_in[9];
    const int E = in_sizes[6];

    float* out = (float*)d_out;
    float* outXq = out;                 // NQ*DD
    float* outXt = out + NQ * DD;       // NT*DD

    float* ws = (float*)d_ws;
    float* Yqa = ws;                    // NQ*DD
    float* Yqb = Yqa + NQ * DD;         // NQ*DD
    float* s = Yqb + NQ * DD;           // NT
    float* a = s + NT;                  // E
    float* beta = a + E;                // E

    // Output 0 is Xq unchanged.
    hipMemcpyAsync(outXq, Xq, NQ * DD * sizeof(float), hipMemcpyDeviceToDevice, stream);
    hipMemsetAsync(s, 0, NT * sizeof(float), stream);

    yq_kernel<<<NQ, DD, 0, stream>>>(Xq, Wa, Wb, Yqa, Yqb);

    const int eblocks = 4096, ethreads = 256;
    edgeA_kernel<<<eblocks, ethreads, 0, stream>>>(Yqa, Yqb, Xt, ba, bb, u_idx, v_idx,
                                                   a, beta, s, E);
    init_rows_kernel<<<(NT * DD) / 256, 256, 0, stream>>>(Xt, s, outXt);
    consensus_kernel<<<(MM * DD) / 256, 256, 0, stream>>>(Xq, uc, vc, outXt);
    edgeB_kernel<<<eblocks, ethreads, 0, stream>>>(Xq, Xt, u_idx, v_idx, a, beta, s,
                                                   outXt, E);
}

// Round 2
// 748.176 us; speedup vs baseline: 1.1594x; 1.1594x over previous
//
#include <hip/hip_runtime.h>

#define NQ 2048
#define NT 131072
#define DD 64
#define MM 1024
#define SCAN_BLK 1024
#define NBLK (NT / SCAN_BLK)   // 128

// Yq = Xq @ W for both weight matrices. One block per row, 64 threads = cols.
__global__ void yq_kernel(const float* __restrict__ Xq,
                          const float* __restrict__ Wa,
                          const float* __restrict__ Wb,
                          float* __restrict__ Yqa,
                          float* __restrict__ Yqb) {
    int r = blockIdx.x;
    int j = threadIdx.x;
    float sa = 0.f, sb = 0.f;
#pragma unroll
    for (int k = 0; k < DD; ++k) {
        float x = Xq[r * DD + k];
        sa = fmaf(x, Wa[k * DD + j], sa);
        sb = fmaf(x, Wb[k * DD + j], sb);
    }
    Yqa[r * DD + j] = sa;
    Yqb[r * DD + j] = sb;
}

__global__ void hist_kernel(const int* __restrict__ v_idx, int* __restrict__ cnt, int E) {
    int e = blockIdx.x * blockDim.x + threadIdx.x;
    if (e < E) atomicAdd(&cnt[v_idx[e]], 1);
}

// Per-block inclusive scan (Hillis-Steele) of cnt -> offs; block totals -> bsums.
__global__ void scan1_kernel(const int* __restrict__ cnt, int* __restrict__ offs,
                             int* __restrict__ bsums) {
    __shared__ int tmp[SCAN_BLK];
    int tid = threadIdx.x;
    int g = blockIdx.x * SCAN_BLK + tid;
    tmp[tid] = cnt[g];
    __syncthreads();
    for (int off = 1; off < SCAN_BLK; off <<= 1) {
        int y = (tid >= off) ? tmp[tid - off] : 0;
        __syncthreads();
        tmp[tid] += y;
        __syncthreads();
    }
    offs[g] = tmp[tid];
    if (tid == SCAN_BLK - 1) bsums[blockIdx.x] = tmp[tid];
}

// Exclusive scan of the 128 block sums, in place. One block of NBLK threads.
__global__ void scan2_kernel(int* __restrict__ bsums) {
    __shared__ int tmp[NBLK];
    int tid = threadIdx.x;
    int orig = bsums[tid];
    tmp[tid] = orig;
    __syncthreads();
    for (int off = 1; off < NBLK; off <<= 1) {
        int y = (tid >= off) ? tmp[tid - off] : 0;
        __syncthreads();
        tmp[tid] += y;
        __syncthreads();
    }
    bsums[tid] = tmp[tid] - orig;   // exclusive
}

// offs -> global EXCLUSIVE scan (start positions).
__global__ void scan3_kernel(const int* __restrict__ cnt, int* __restrict__ offs,
                             const int* __restrict__ bsums) {
    int tid = threadIdx.x;
    int g = blockIdx.x * SCAN_BLK + tid;
    offs[g] = offs[g] - cnt[g] + bsums[blockIdx.x];
}

// Scatter u into CSR order. Afterwards offs[v] == end of segment v.
__global__ void scatter_kernel(const int* __restrict__ u_idx, const int* __restrict__ v_idx,
                               int* __restrict__ offs, int* __restrict__ u_sorted, int E) {
    int e = blockIdx.x * blockDim.x + threadIdx.x;
    if (e < E) {
        int pos = atomicAdd(&offs[v_idx[e]], 1);
        u_sorted[pos] = u_idx[e];
    }
}

// One wave per target row v. Two passes over the row's edge segment:
//  pass1: alpha/beta via cross-lane dot products; a=exp(alpha) cached in lane regs; s=sum a
//  pass2: acc += (a/s + 1e-10) * ((1-beta)*Xq[u] + beta*Xt[v]); single coalesced store.
__global__ void row_kernel(const float* __restrict__ Xq,
                           const float* __restrict__ Xt,
                           const float* __restrict__ Yqa,
                           const float* __restrict__ Yqb,
                           const float* __restrict__ ba,
                           const float* __restrict__ bb,
                           const int* __restrict__ offs,   // post-scatter: end positions
                           const int* __restrict__ cnt,
                           const int* __restrict__ u_sorted,
                           float* __restrict__ outXt) {
    int gtid = blockIdx.x * blockDim.x + threadIdx.x;
    int lane = gtid & 63;
    int wid = gtid >> 6;
    int nw = (gridDim.x * blockDim.x) >> 6;
    float ba0 = ba[0];
    float bb0 = bb[0];

    for (int v = wid; v < NT; v += nw) {
        int end = offs[v];
        int deg = cnt[v];
        int start = end - deg;
        float xt = Xt[v * DD + lane];
        if (deg == 0) {
            outXt[v * DD + lane] = xt;
            continue;
        }
        float r0a = 0.f, r0b = 0.f, r1a = 0.f, r1b = 0.f;  // lane-slot cache (<=128 edges)
        float s = 0.f;
        for (int k = 0; k < deg; ++k) {
            int u = u_sorted[start + k];
            float pa = Yqa[u * DD + lane] * xt;
            float pb = Yqb[u * DD + lane] * xt;
#pragma unroll
            for (int off = 32; off > 0; off >>= 1) {
                pa += __shfl_xor(pa, off, 64);
                pb += __shfl_xor(pb, off, 64);
            }
            float la = pa + ba0;
            float alpha = la > 0.f ? la : expm1f(la);          // ELU
            float a = expf(alpha);
            float beta = 1.f / (1.f + expf(-(pb + bb0)));
            s += a;
            if (k < 128 && (k & 63) == lane) {
                if (k < 64) { r0a = a; r0b = beta; }
                else        { r1a = a; r1b = beta; }
            }
        }
        float inv_s = 1.f / s;
        float acc = 0.f;
        if (deg <= 128) {
            for (int k = 0; k < deg; ++k) {
                int u = u_sorted[start + k];
                float a    = __shfl(k < 64 ? r0a : r1a, k & 63, 64);
                float beta = __shfl(k < 64 ? r0b : r1b, k & 63, 64);
                float w = a * inv_s + 1e-10f;
                acc += w * ((1.f - beta) * Xq[u * DD + lane] + beta * xt);
            }
        } else {
            // astronomically rare (Poisson mean ~15): recompute alpha/beta
            for (int k = 0; k < deg; ++k) {
                int u = u_sorted[start + k];
                float pa = Yqa[u * DD + lane] * xt;
                float pb = Yqb[u * DD + lane] * xt;
#pragma unroll
                for (int off = 32; off > 0; off >>= 1) {
                    pa += __shfl_xor(pa, off, 64);
                    pb += __shfl_xor(pb, off, 64);
                }
                float la = pa + ba0;
                float alpha = la > 0.f ? la : expm1f(la);
                float a = expf(alpha);
                float beta = 1.f / (1.f + expf(-(pb + bb0)));
                float w = a * inv_s + 1e-10f;
                acc += w * ((1.f - beta) * Xq[u * DD + lane] + beta * xt);
            }
        }
        outXt[v * DD + lane] = acc;
    }
}

// Consensus overwrite: outXt[vc[i]] = Xq[uc[i]]  (these rows have deg==0).
__global__ void consensus_kernel(const float* __restrict__ Xq,
                                 const int* __restrict__ uc,
                                 const int* __restrict__ vc,
                                 float* __restrict__ outXt) {
    int idx = blockIdx.x * blockDim.x + threadIdx.x;   // over MM*DD
    int i = idx >> 6;
    int d = idx & 63;
    outXt[vc[i] * DD + d] = Xq[uc[i] * DD + d];
}

extern "C" void kernel_launch(void* const* d_in, const int* in_sizes, int n_in,
                              void* d_out, int out_size, void* d_ws, size_t ws_size,
                              hipStream_t stream) {
    const float* Xq = (const float*)d_in[0];
    const float* Xt = (const float*)d_in[1];
    const float* Wa = (const float*)d_in[2];
    const float* ba = (const float*)d_in[3];
    const float* Wb = (const float*)d_in[4];
    const float* bb = (const float*)d_in[5];
    const int* u_idx = (const int*)d_in[6];
    const int* v_idx = (const int*)d_in[7];
    const int* uc = (const int*)d_in[8];
    const int* vc = (const int*)d_in[9];
    const int E = in_sizes[6];

    float* out = (float*)d_out;
    float* outXq = out;                 // NQ*DD
    float* outXt = out + NQ * DD;       // NT*DD

    char* ws = (char*)d_ws;
    float* Yqa = (float*)ws;                       ws += NQ * DD * sizeof(float);
    float* Yqb = (float*)ws;                       ws += NQ * DD * sizeof(float);
    int* cnt = (int*)ws;                           ws += NT * sizeof(int);
    int* offs = (int*)ws;                          ws += NT * sizeof(int);
    int* bsums = (int*)ws;                         ws += NBLK * sizeof(int);
    int* u_sorted = (int*)ws;                      ws += (size_t)E * sizeof(int);

    // Output 0 is Xq unchanged.
    hipMemcpyAsync(outXq, Xq, NQ * DD * sizeof(float), hipMemcpyDeviceToDevice, stream);
    hipMemsetAsync(cnt, 0, NT * sizeof(int), stream);

    yq_kernel<<<NQ, DD, 0, stream>>>(Xq, Wa, Wb, Yqa, Yqb);

    int eblk = (E + 255) / 256;
    hist_kernel<<<eblk, 256, 0, stream>>>(v_idx, cnt, E);
    scan1_kernel<<<NBLK, SCAN_BLK, 0, stream>>>(cnt, offs, bsums);
    scan2_kernel<<<1, NBLK, 0, stream>>>(bsums);
    scan3_kernel<<<NBLK, SCAN_BLK, 0, stream>>>(cnt, offs, bsums);
    scatter_kernel<<<eblk, 256, 0, stream>>>(u_idx, v_idx, offs, u_sorted, E);

    row_kernel<<<2048, 256, 0, stream>>>(Xq, Xt, Yqa, Yqb, ba, bb, offs, cnt, u_sorted, outXt);
    consensus_kernel<<<(MM * DD) / 256, 256, 0, stream>>>(Xq, uc, vc, outXt);
}

// Round 3
// 540.015 us; speedup vs baseline: 1.6063x; 1.3855x over previous
//
#include <hip/hip_runtime.h>

#define NQ 2048
#define NT 131072
#define DD 64
#define MM 1024
#define SCAN_BLK 1024
#define NBLK (NT / SCAN_BLK)   // 128

// Yq = Xq @ W for both weight matrices. One block per row, 64 threads = cols.
__global__ void yq_kernel(const float* __restrict__ Xq,
                          const float* __restrict__ Wa,
                          const float* __restrict__ Wb,
                          float* __restrict__ Yqa,
                          float* __restrict__ Yqb) {
    int r = blockIdx.x;
    int j = threadIdx.x;
    float sa = 0.f, sb = 0.f;
#pragma unroll
    for (int k = 0; k < DD; ++k) {
        float x = Xq[r * DD + k];
        sa = fmaf(x, Wa[k * DD + j], sa);
        sb = fmaf(x, Wb[k * DD + j], sb);
    }
    Yqa[r * DD + j] = sa;
    Yqb[r * DD + j] = sb;
}

__global__ void hist_kernel(const int* __restrict__ v_idx, int* __restrict__ cnt, int E) {
    int e = blockIdx.x * blockDim.x + threadIdx.x;
    if (e < E) atomicAdd(&cnt[v_idx[e]], 1);
}

// Per-block inclusive scan (Hillis-Steele) of cnt -> offs; block totals -> bsums.
__global__ void scan1_kernel(const int* __restrict__ cnt, int* __restrict__ offs,
                             int* __restrict__ bsums) {
    __shared__ int tmp[SCAN_BLK];
    int tid = threadIdx.x;
    int g = blockIdx.x * SCAN_BLK + tid;
    tmp[tid] = cnt[g];
    __syncthreads();
    for (int off = 1; off < SCAN_BLK; off <<= 1) {
        int y = (tid >= off) ? tmp[tid - off] : 0;
        __syncthreads();
        tmp[tid] += y;
        __syncthreads();
    }
    offs[g] = tmp[tid];
    if (tid == SCAN_BLK - 1) bsums[blockIdx.x] = tmp[tid];
}

// Exclusive scan of the 128 block sums, in place. One block of NBLK threads.
__global__ void scan2_kernel(int* __restrict__ bsums) {
    __shared__ int tmp[NBLK];
    int tid = threadIdx.x;
    int orig = bsums[tid];
    tmp[tid] = orig;
    __syncthreads();
    for (int off = 1; off < NBLK; off <<= 1) {
        int y = (tid >= off) ? tmp[tid - off] : 0;
        __syncthreads();
        tmp[tid] += y;
        __syncthreads();
    }
    bsums[tid] = tmp[tid] - orig;   // exclusive
}

// offs -> global EXCLUSIVE scan (start positions).
__global__ void scan3_kernel(const int* __restrict__ cnt, int* __restrict__ offs,
                             const int* __restrict__ bsums) {
    int tid = threadIdx.x;
    int g = blockIdx.x * SCAN_BLK + tid;
    offs[g] = offs[g] - cnt[g] + bsums[blockIdx.x];
}

// Scatter u into CSR order. Afterwards offs[v] == end of segment v.
__global__ void scatter_kernel(const int* __restrict__ u_idx, const int* __restrict__ v_idx,
                               int* __restrict__ offs, int* __restrict__ u_sorted, int E) {
    int e = blockIdx.x * blockDim.x + threadIdx.x;
    if (e < E) {
        int pos = atomicAdd(&offs[v_idx[e]], 1);
        u_sorted[pos] = u_idx[e];
    }
}

// Fused score + softmax + aggregate. One wave per target row v.
// Phase 1 (per chunk of <=64 edges): 4 groups of 16 lanes; each group computes one
// edge's two 64-dots via float4 loads + 4-step 16-lane shuffle reduce. a=exp(elu),
// beta=sigmoid computed at full utilization; results cached per-lane
// (lane l16 of group g keeps edge g+4*l16).
// Phase 2: serial over chunk edges; a,beta broadcast via one shuffle each;
// acc += a*h, s += a, hsum += h; h=(1-beta)*Xq[u]+beta*xt (coalesced Xq row load).
// Final: out = acc/s + 1e-10*hsum  (== sum_k (a_k/s + 1e-10) * h_k).
__global__ __launch_bounds__(256) void row_fused_kernel(
        const float* __restrict__ Xq,
        const float* __restrict__ Xt,
        const float* __restrict__ Yqa,
        const float* __restrict__ Yqb,
        const float* __restrict__ ba,
        const float* __restrict__ bb,
        const int* __restrict__ offs,   // post-scatter: end positions
        const int* __restrict__ cnt,
        const int* __restrict__ u_sorted,
        float* __restrict__ outXt) {
    int gtid = blockIdx.x * blockDim.x + threadIdx.x;
    int lane = gtid & 63;
    int wid = gtid >> 6;
    int nw = (gridDim.x * blockDim.x) >> 6;
    int l16 = lane & 15;
    int g = lane >> 4;
    float ba0 = ba[0];
    float bb0 = bb[0];

    for (int v = wid; v < NT; v += nw) {
        int deg = cnt[v];
        int end = offs[v];
        int start = end - deg;
        float xt_f = Xt[v * DD + lane];
        if (deg == 0) {
            outXt[v * DD + lane] = xt_f;
            continue;
        }
        float4 xt4 = ((const float4*)(Xt + v * DD))[l16];

        float s = 0.f, acc = 0.f, hsum = 0.f;
        for (int base = 0; base < deg; base += 64) {
            int nc = min(64, deg - base);
            float reg_a = 0.f, reg_b = 0.f;
            // Phase 1: scores, 4 edges per wave-iteration
            for (int kk = g; kk < nc; kk += 4) {
                int u = u_sorted[start + base + kk];
                float4 ya = ((const float4*)(Yqa + u * DD))[l16];
                float4 yb = ((const float4*)(Yqb + u * DD))[l16];
                float pa = fmaf(ya.x, xt4.x, fmaf(ya.y, xt4.y, fmaf(ya.z, xt4.z, ya.w * xt4.w)));
                float pb = fmaf(yb.x, xt4.x, fmaf(yb.y, xt4.y, fmaf(yb.z, xt4.z, yb.w * xt4.w)));
#pragma unroll
                for (int off = 8; off > 0; off >>= 1) {
                    pa += __shfl_xor(pa, off, 64);
                    pb += __shfl_xor(pb, off, 64);
                }
                float la = pa + ba0;
                float alpha = la > 0.f ? la : expm1f(la);   // ELU
                float a = expf(alpha);
                float beta = 1.f / (1.f + expf(-(pb + bb0)));
                if ((kk >> 2) == l16) { reg_a = a; reg_b = beta; }
            }
            // Phase 2: aggregate
            for (int k = 0; k < nc; ++k) {
                int src = ((k & 3) << 4) + (k >> 2);
                float a = __shfl(reg_a, src, 64);
                float beta = __shfl(reg_b, src, 64);
                int u = u_sorted[start + base + k];
                float xq = Xq[u * DD + lane];
                float h = fmaf(beta, xt_f - xq, xq);   // (1-beta)*xq + beta*xt
                s += a;
                acc = fmaf(a, h, acc);
                hsum += h;
            }
        }
        outXt[v * DD + lane] = acc / s + 1e-10f * hsum;
    }
}

// Consensus overwrite: outXt[vc[i]] = Xq[uc[i]]  (these rows have deg==0).
__global__ void consensus_kernel(const float* __restrict__ Xq,
                                 const int* __restrict__ uc,
                                 const int* __restrict__ vc,
                                 float* __restrict__ outXt) {
    int idx = blockIdx.x * blockDim.x + threadIdx.x;   // over MM*DD
    int i = idx >> 6;
    int d = idx & 63;
    outXt[vc[i] * DD + d] = Xq[uc[i] * DD + d];
}

extern "C" void kernel_launch(void* const* d_in, const int* in_sizes, int n_in,
                              void* d_out, int out_size, void* d_ws, size_t ws_size,
                              hipStream_t stream) {
    const float* Xq = (const float*)d_in[0];
    const float* Xt = (const float*)d_in[1];
    const float* Wa = (const float*)d_in[2];
    const float* ba = (const float*)d_in[3];
    const float* Wb = (const float*)d_in[4];
    const float* bb = (const float*)d_in[5];
    const int* u_idx = (const int*)d_in[6];
    const int* v_idx = (const int*)d_in[7];
    const int* uc = (const int*)d_in[8];
    const int* vc = (const int*)d_in[9];
    const int E = in_sizes[6];

    float* out = (float*)d_out;
    float* outXq = out;                 // NQ*DD
    float* outXt = out + NQ * DD;       // NT*DD

    char* ws = (char*)d_ws;
    float* Yqa = (float*)ws;                       ws += NQ * DD * sizeof(float);
    float* Yqb = (float*)ws;                       ws += NQ * DD * sizeof(float);
    int* cnt = (int*)ws;                           ws += NT * sizeof(int);
    int* offs = (int*)ws;                          ws += NT * sizeof(int);
    int* bsums = (int*)ws;                         ws += NBLK * sizeof(int);
    int* u_sorted = (int*)ws;                      ws += (size_t)E * sizeof(int);

    // Output 0 is Xq unchanged.
    hipMemcpyAsync(outXq, Xq, NQ * DD * sizeof(float), hipMemcpyDeviceToDevice, stream);
    hipMemsetAsync(cnt, 0, NT * sizeof(int), stream);

    yq_kernel<<<NQ, DD, 0, stream>>>(Xq, Wa, Wb, Yqa, Yqb);

    int eblk = (E + 255) / 256;
    hist_kernel<<<eblk, 256, 0, stream>>>(v_idx, cnt, E);
    scan1_kernel<<<NBLK, SCAN_BLK, 0, stream>>>(cnt, offs, bsums);
    scan2_kernel<<<1, NBLK, 0, stream>>>(bsums);
    scan3_kernel<<<NBLK, SCAN_BLK, 0, stream>>>(cnt, offs, bsums);
    scatter_kernel<<<eblk, 256, 0, stream>>>(u_idx, v_idx, offs, u_sorted, E);

    row_fused_kernel<<<4096, 256, 0, stream>>>(Xq, Xt, Yqa, Yqb, ba, bb, offs, cnt,
                                               u_sorted, outXt);
    consensus_kernel<<<(MM * DD) / 256, 256, 0, stream>>>(Xq, uc, vc, outXt);
}

// Round 4
// 375.899 us; speedup vs baseline: 2.3076x; 1.4366x over previous
//
#include <hip/hip_runtime.h>
#include <hip/hip_fp16.h>

#define NQ 2048
#define NT 131072
#define DD 64
#define MM 1024
#define SCAN_BLK 1024
#define NBLK (NT / SCAN_BLK)   // 128

// Yq = Xq @ W for both weight matrices. 4 rows per 256-thread block.
__global__ void yq_kernel(const float* __restrict__ Xq,
                          const float* __restrict__ Wa,
                          const float* __restrict__ Wb,
                          float* __restrict__ Yqa,
                          float* __restrict__ Yqb) {
    int r = blockIdx.x * 4 + (threadIdx.x >> 6);
    int j = threadIdx.x & 63;
    float sa = 0.f, sb = 0.f;
#pragma unroll
    for (int k = 0; k < DD; ++k) {
        float x = Xq[r * DD + k];
        sa = fmaf(x, Wa[k * DD + j], sa);
        sb = fmaf(x, Wb[k * DD + j], sb);
    }
    Yqa[r * DD + j] = sa;
    Yqb[r * DD + j] = sb;
}

// Histogram + within-segment rank from the SAME atomic (halves total atomics).
__global__ void hist_rank_kernel(const int* __restrict__ v_idx, int* __restrict__ cnt,
                                 unsigned short* __restrict__ rank, int E) {
    int e = blockIdx.x * blockDim.x + threadIdx.x;
    if (e < E) rank[e] = (unsigned short)atomicAdd(&cnt[v_idx[e]], 1);
}

// Per-block inclusive scan (Hillis-Steele) of cnt -> offs; block totals -> bsums.
__global__ void scan1_kernel(const int* __restrict__ cnt, int* __restrict__ offs,
                             int* __restrict__ bsums) {
    __shared__ int tmp[SCAN_BLK];
    int tid = threadIdx.x;
    int g = blockIdx.x * SCAN_BLK + tid;
    tmp[tid] = cnt[g];
    __syncthreads();
    for (int off = 1; off < SCAN_BLK; off <<= 1) {
        int y = (tid >= off) ? tmp[tid - off] : 0;
        __syncthreads();
        tmp[tid] += y;
        __syncthreads();
    }
    offs[g] = tmp[tid];
    if (tid == SCAN_BLK - 1) bsums[blockIdx.x] = tmp[tid];
}

// Exclusive scan of the 128 block sums, in place. One block of NBLK threads.
__global__ void scan2_kernel(int* __restrict__ bsums) {
    __shared__ int tmp[NBLK];
    int tid = threadIdx.x;
    int orig = bsums[tid];
    tmp[tid] = orig;
    __syncthreads();
    for (int off = 1; off < NBLK; off <<= 1) {
        int y = (tid >= off) ? tmp[tid - off] : 0;
        __syncthreads();
        tmp[tid] += y;
        __syncthreads();
    }
    bsums[tid] = tmp[tid] - orig;   // exclusive
}

// offs -> global EXCLUSIVE scan (segment start positions). offs stays immutable after.
__global__ void scan3_kernel(const int* __restrict__ cnt, int* __restrict__ offs,
                             const int* __restrict__ bsums) {
    int tid = threadIdx.x;
    int g = blockIdx.x * SCAN_BLK + tid;
    offs[g] = offs[g] - cnt[g] + bsums[blockIdx.x];
}

// Edge-parallel score + fused scatter. 4 groups of 16 lanes; each group one edge.
// Dots via float4 loads + 4 xor-shuffles (within group); transcendentals at full
// lane utilization. Lane 0 of each group writes rec[offs[v]+rank[e]] =
// {a, pack(u:16, beta:fp16)} -- scatter needs NO atomic.
__global__ __launch_bounds__(256) void score_scatter_kernel(
        const float* __restrict__ Xt,
        const float* __restrict__ Yqa,
        const float* __restrict__ Yqb,
        const float* __restrict__ ba,
        const float* __restrict__ bb,
        const int* __restrict__ u_idx,
        const int* __restrict__ v_idx,
        const int* __restrict__ offs,
        const unsigned short* __restrict__ rank,
        float2* __restrict__ rec, int E) {
    int gtid = blockIdx.x * blockDim.x + threadIdx.x;
    int lane = gtid & 63;
    int l16 = lane & 15;
    int g = lane >> 4;
    int wid = gtid >> 6;
    int nw = (gridDim.x * blockDim.x) >> 6;
    float ba0 = ba[0];
    float bb0 = bb[0];

    for (int ebase = wid * 4; ebase < E; ebase += nw * 4) {
        int e = ebase + g;
        bool valid = (e < E);
        int ee = valid ? e : 0;
        int u = u_idx[ee];
        int v = v_idx[ee];
        float4 xt4 = ((const float4*)(Xt + (size_t)v * DD))[l16];
        float4 ya = ((const float4*)(Yqa + u * DD))[l16];
        float4 yb = ((const float4*)(Yqb + u * DD))[l16];
        float pa = fmaf(ya.x, xt4.x, fmaf(ya.y, xt4.y, fmaf(ya.z, xt4.z, ya.w * xt4.w)));
        float pb = fmaf(yb.x, xt4.x, fmaf(yb.y, xt4.y, fmaf(yb.z, xt4.z, yb.w * xt4.w)));
#pragma unroll
        for (int off = 1; off < 16; off <<= 1) {
            pa += __shfl_xor(pa, off, 64);
            pb += __shfl_xor(pb, off, 64);
        }
        float la = pa + ba0;
        float alpha = la > 0.f ? la : expm1f(la);   // ELU
        float a = expf(alpha);
        float beta = 1.f / (1.f + expf(-(pb + bb0)));
        if (valid && l16 == 0) {
            int pos = offs[v] + (int)rank[e];
            unsigned packed = ((unsigned)u << 16) |
                              (unsigned)__half_as_ushort(__float2half(beta));
            rec[pos] = make_float2(a, __uint_as_float(packed));
        }
    }
}

// Aggregate-only pass. 4 rows per wave (16 lanes x float4 per row).
// Per edge: one uniform 8B rec load + one coalesced float4 Xq load + FMAs.
// out = acc/s + 1e-10*hsum  ==  sum_k (a_k/s + 1e-10) * h_k.
__global__ __launch_bounds__(256) void row_agg_kernel(
        const float* __restrict__ Xq,
        const float* __restrict__ Xt,
        const int* __restrict__ offs,
        const int* __restrict__ cnt,
        const float2* __restrict__ rec,
        float* __restrict__ outXt) {
    int gtid = blockIdx.x * blockDim.x + threadIdx.x;
    int lane = gtid & 63;
    int l16 = lane & 15;
    int g = lane >> 4;
    int wid = gtid >> 6;
    int nw = (gridDim.x * blockDim.x) >> 6;

    for (int vbase = wid * 4; vbase < NT; vbase += nw * 4) {
        int v = vbase + g;
        int deg = cnt[v];
        int start = offs[v];
        float4 xt4 = ((const float4*)(Xt + (size_t)v * DD))[l16];
        float4 acc = make_float4(0.f, 0.f, 0.f, 0.f);
        float4 hsum = make_float4(0.f, 0.f, 0.f, 0.f);
        float s = 0.f;
        for (int k = 0; k < deg; ++k) {
            float2 r = rec[start + k];
            float a = r.x;
            unsigned p = __float_as_uint(r.y);
            int u = (int)(p >> 16);
            float beta = __half2float(__ushort_as_half((unsigned short)(p & 0xFFFFu)));
            float4 xq4 = ((const float4*)(Xq + u * DD))[l16];
            float4 h;
            h.x = fmaf(beta, xt4.x - xq4.x, xq4.x);
            h.y = fmaf(beta, xt4.y - xq4.y, xq4.y);
            h.z = fmaf(beta, xt4.z - xq4.z, xq4.z);
            h.w = fmaf(beta, xt4.w - xq4.w, xq4.w);
            acc.x = fmaf(a, h.x, acc.x);
            acc.y = fmaf(a, h.y, acc.y);
            acc.z = fmaf(a, h.z, acc.z);
            acc.w = fmaf(a, h.w, acc.w);
            hsum.x += h.x; hsum.y += h.y; hsum.z += h.z; hsum.w += h.w;
            s += a;
        }
        float4 o;
        if (deg > 0) {
            float inv = 1.f / s;
            o.x = fmaf(acc.x, inv, 1e-10f * hsum.x);
            o.y = fmaf(acc.y, inv, 1e-10f * hsum.y);
            o.z = fmaf(acc.z, inv, 1e-10f * hsum.z);
            o.w = fmaf(acc.w, inv, 1e-10f * hsum.w);
        } else {
            o = xt4;
        }
        ((float4*)(outXt + (size_t)v * DD))[l16] = o;
    }
}

// Consensus overwrite: outXt[vc[i]] = Xq[uc[i]]  (these rows have deg==0).
__global__ void consensus_kernel(const float* __restrict__ Xq,
                                 const int* __restrict__ uc,
                                 const int* __restrict__ vc,
                                 float* __restrict__ outXt) {
    int idx = blockIdx.x * blockDim.x + threadIdx.x;   // over MM*DD
    int i = idx >> 6;
    int d = idx & 63;
    outXt[vc[i] * DD + d] = Xq[uc[i] * DD + d];
}

extern "C" void kernel_launch(void* const* d_in, const int* in_sizes, int n_in,
                              void* d_out, int out_size, void* d_ws, size_t ws_size,
                              hipStream_t stream) {
    const float* Xq = (const float*)d_in[0];
    const float* Xt = (const float*)d_in[1];
    const float* Wa = (const float*)d_in[2];
    const float* ba = (const float*)d_in[3];
    const float* Wb = (const float*)d_in[4];
    const float* bb = (const float*)d_in[5];
    const int* u_idx = (const int*)d_in[6];
    const int* v_idx = (const int*)d_in[7];
    const int* uc = (const int*)d_in[8];
    const int* vc = (const int*)d_in[9];
    const int E = in_sizes[6];

    float* out = (float*)d_out;
    float* outXq = out;                 // NQ*DD
    float* outXt = out + NQ * DD;       // NT*DD

    char* ws = (char*)d_ws;
    float* Yqa = (float*)ws;                 ws += NQ * DD * sizeof(float);     // 512K
    float* Yqb = (float*)ws;                 ws += NQ * DD * sizeof(float);     // 512K
    int* cnt = (int*)ws;                     ws += NT * sizeof(int);            // 512K
    int* offs = (int*)ws;                    ws += NT * sizeof(int);            // 512K
    float2* rec = (float2*)ws;               ws += (size_t)E * sizeof(float2);  // 16M
    int* bsums = (int*)ws;                   ws += 4096;                        // pad
    unsigned short* rank = (unsigned short*)ws;  ws += (size_t)E * sizeof(unsigned short); // 4M

    // Output 0 is Xq unchanged.
    hipMemcpyAsync(outXq, Xq, NQ * DD * sizeof(float), hipMemcpyDeviceToDevice, stream);
    hipMemsetAsync(cnt, 0, NT * sizeof(int), stream);

    yq_kernel<<<NQ / 4, 256, 0, stream>>>(Xq, Wa, Wb, Yqa, Yqb);

    int eblk = (E + 255) / 256;
    hist_rank_kernel<<<eblk, 256, 0, stream>>>(v_idx, cnt, rank, E);
    scan1_kernel<<<NBLK, SCAN_BLK, 0, stream>>>(cnt, offs, bsums);
    scan2_kernel<<<1, NBLK, 0, stream>>>(bsums);
    scan3_kernel<<<NBLK, SCAN_BLK, 0, stream>>>(cnt, offs, bsums);

    score_scatter_kernel<<<8192, 256, 0, stream>>>(Xt, Yqa, Yqb, ba, bb, u_idx, v_idx,
                                                   offs, rank, rec, E);
    row_agg_kernel<<<8192, 256, 0, stream>>>(Xq, Xt, offs, cnt, rec, outXt);
    consensus_kernel<<<(MM * DD) / 256, 256, 0, stream>>>(Xq, uc, vc, outXt);
}

// Round 5
// 335.155 us; speedup vs baseline: 2.5881x; 1.1216x over previous
//
#include <hip/hip_runtime.h>

#define NQ 2048
#define NT 131072
#define DD 64
#define MM 1024
#define SCAN_BLK 1024
#define NBLK (NT / SCAN_BLK)   // 128

// Yq = Xq @ W for both weight matrices. 4 rows per 256-thread block.
__global__ void yq_kernel(const float* __restrict__ Xq,
                          const float* __restrict__ Wa,
                          const float* __restrict__ Wb,
                          float* __restrict__ Yqa,
                          float* __restrict__ Yqb) {
    int r = blockIdx.x * 4 + (threadIdx.x >> 6);
    int j = threadIdx.x & 63;
    float sa = 0.f, sb = 0.f;
#pragma unroll
    for (int k = 0; k < DD; ++k) {
        float x = Xq[r * DD + k];
        sa = fmaf(x, Wa[k * DD + j], sa);
        sb = fmaf(x, Wb[k * DD + j], sb);
    }
    Yqa[r * DD + j] = sa;
    Yqb[r * DD + j] = sb;
}

// Histogram + within-segment rank from the SAME atomic.
__global__ void hist_rank_kernel(const int* __restrict__ v_idx, int* __restrict__ cnt,
                                 unsigned short* __restrict__ rank, int E) {
    int e = blockIdx.x * blockDim.x + threadIdx.x;
    if (e < E) rank[e] = (unsigned short)atomicAdd(&cnt[v_idx[e]], 1);
}

// Per-block inclusive scan (Hillis-Steele) of cnt -> offs; block totals -> bsums.
__global__ void scan1_kernel(const int* __restrict__ cnt, int* __restrict__ offs,
                             int* __restrict__ bsums) {
    __shared__ int tmp[SCAN_BLK];
    int tid = threadIdx.x;
    int g = blockIdx.x * SCAN_BLK + tid;
    tmp[tid] = cnt[g];
    __syncthreads();
    for (int off = 1; off < SCAN_BLK; off <<= 1) {
        int y = (tid >= off) ? tmp[tid - off] : 0;
        __syncthreads();
        tmp[tid] += y;
        __syncthreads();
    }
    offs[g] = tmp[tid];
    if (tid == SCAN_BLK - 1) bsums[blockIdx.x] = tmp[tid];
}

// Exclusive scan of the 128 block sums, in place. One block of NBLK threads.
__global__ void scan2_kernel(int* __restrict__ bsums) {
    __shared__ int tmp[NBLK];
    int tid = threadIdx.x;
    int orig = bsums[tid];
    tmp[tid] = orig;
    __syncthreads();
    for (int off = 1; off < NBLK; off <<= 1) {
        int y = (tid >= off) ? tmp[tid - off] : 0;
        __syncthreads();
        tmp[tid] += y;
        __syncthreads();
    }
    bsums[tid] = tmp[tid] - orig;   // exclusive
}

// offs -> global EXCLUSIVE scan (segment start positions). Immutable afterwards.
__global__ void scan3_kernel(const int* __restrict__ cnt, int* __restrict__ offs,
                             const int* __restrict__ bsums) {
    int tid = threadIdx.x;
    int g = blockIdx.x * SCAN_BLK + tid;
    offs[g] = offs[g] - cnt[g] + bsums[blockIdx.x];
}

// Atomic-free scatter of u into CSR order using precomputed rank.
__global__ void scatter_u_kernel(const int* __restrict__ u_idx,
                                 const int* __restrict__ v_idx,
                                 const unsigned short* __restrict__ rank,
                                 const int* __restrict__ offs,
                                 int* __restrict__ u_sorted, int E) {
    int e = blockIdx.x * blockDim.x + threadIdx.x;
    if (e < E) u_sorted[offs[v_idx[e]] + (int)rank[e]] = u_idx[e];
}

// Fused score + softmax + aggregate, CSR row order. One wave per row.
// 4 groups x 16 lanes; 4 edges in flight (one per group). Per edge: float4
// gathers of Yqa/Yqb/Xq rows (all L2-resident, u<2048), group-local dot via
// 4-step xor reduce, full-utilization ELU/exp/sigmoid, per-group partial
// acc/hsum/s. Per row: 2-step cross-group reduce, single coalesced store.
// Xt is read row-sequentially (streamed once), never gathered.
// out = acc/s + 1e-10*hsum  ==  sum_k (a_k/s + 1e-10) * h_k.
__global__ __launch_bounds__(256) void row_score_agg_kernel(
        const float* __restrict__ Xq,
        const float* __restrict__ Xt,
        const float* __restrict__ Yqa,
        const float* __restrict__ Yqb,
        const float* __restrict__ ba,
        const float* __restrict__ bb,
        const int* __restrict__ offs,
        const int* __restrict__ cnt,
        const int* __restrict__ u_sorted,
        float* __restrict__ outXt) {
    int gtid = blockIdx.x * blockDim.x + threadIdx.x;
    int lane = gtid & 63;
    int l16 = lane & 15;
    int g = lane >> 4;
    int wid = gtid >> 6;
    int nw = (gridDim.x * blockDim.x) >> 6;
    float ba0 = ba[0];
    float bb0 = bb[0];

    for (int v = wid; v < NT; v += nw) {
        int deg = cnt[v];
        float4 xt4 = ((const float4*)(Xt + (size_t)v * DD))[l16];
        if (deg == 0) {
            if (g == 0) ((float4*)(outXt + (size_t)v * DD))[l16] = xt4;
            continue;
        }
        int start = offs[v];
        float4 acc = make_float4(0.f, 0.f, 0.f, 0.f);
        float4 hsum = make_float4(0.f, 0.f, 0.f, 0.f);
        float s = 0.f;
        for (int k = g; k < deg; k += 4) {
            int u = u_sorted[start + k];
            float4 ya = ((const float4*)(Yqa + u * DD))[l16];
            float4 yb = ((const float4*)(Yqb + u * DD))[l16];
            float pa = fmaf(ya.x, xt4.x, fmaf(ya.y, xt4.y, fmaf(ya.z, xt4.z, ya.w * xt4.w)));
            float pb = fmaf(yb.x, xt4.x, fmaf(yb.y, xt4.y, fmaf(yb.z, xt4.z, yb.w * xt4.w)));
#pragma unroll
            for (int off = 1; off < 16; off <<= 1) {
                pa += __shfl_xor(pa, off, 64);
                pb += __shfl_xor(pb, off, 64);
            }
            float la = pa + ba0;
            float alpha = la > 0.f ? la : expm1f(la);   // ELU
            float a = expf(alpha);
            float beta = 1.f / (1.f + expf(-(pb + bb0)));
            float4 xq4 = ((const float4*)(Xq + u * DD))[l16];
            float4 h;
            h.x = fmaf(beta, xt4.x - xq4.x, xq4.x);     // (1-b)*xq + b*xt
            h.y = fmaf(beta, xt4.y - xq4.y, xq4.y);
            h.z = fmaf(beta, xt4.z - xq4.z, xq4.z);
            h.w = fmaf(beta, xt4.w - xq4.w, xq4.w);
            acc.x = fmaf(a, h.x, acc.x);
            acc.y = fmaf(a, h.y, acc.y);
            acc.z = fmaf(a, h.z, acc.z);
            acc.w = fmaf(a, h.w, acc.w);
            hsum.x += h.x; hsum.y += h.y; hsum.z += h.z; hsum.w += h.w;
            s += a;
        }
        // Cross-group reduce (groups hold partials for the same columns).
#pragma unroll
        for (int off = 16; off < 64; off <<= 1) {
            acc.x += __shfl_xor(acc.x, off, 64);
            acc.y += __shfl_xor(acc.y, off, 64);
            acc.z += __shfl_xor(acc.z, off, 64);
            acc.w += __shfl_xor(acc.w, off, 64);
            hsum.x += __shfl_xor(hsum.x, off, 64);
            hsum.y += __shfl_xor(hsum.y, off, 64);
            hsum.z += __shfl_xor(hsum.z, off, 64);
            hsum.w += __shfl_xor(hsum.w, off, 64);
            s += __shfl_xor(s, off, 64);
        }
        if (g == 0) {
            float inv = 1.f / s;
            float4 o;
            o.x = fmaf(acc.x, inv, 1e-10f * hsum.x);
            o.y = fmaf(acc.y, inv, 1e-10f * hsum.y);
            o.z = fmaf(acc.z, inv, 1e-10f * hsum.z);
            o.w = fmaf(acc.w, inv, 1e-10f * hsum.w);
            ((float4*)(outXt + (size_t)v * DD))[l16] = o;
        }
    }
}

// Consensus overwrite: outXt[vc[i]] = Xq[uc[i]]  (these rows have deg==0).
__global__ void consensus_kernel(const float* __restrict__ Xq,
                                 const int* __restrict__ uc,
                                 const int* __restrict__ vc,
                                 float* __restrict__ outXt) {
    int idx = blockIdx.x * blockDim.x + threadIdx.x;   // over MM*DD
    int i = idx >> 6;
    int d = idx & 63;
    outXt[vc[i] * DD + d] = Xq[uc[i] * DD + d];
}

extern "C" void kernel_launch(void* const* d_in, const int* in_sizes, int n_in,
                              void* d_out, int out_size, void* d_ws, size_t ws_size,
                              hipStream_t stream) {
    const float* Xq = (const float*)d_in[0];
    const float* Xt = (const float*)d_in[1];
    const float* Wa = (const float*)d_in[2];
    const float* ba = (const float*)d_in[3];
    const float* Wb = (const float*)d_in[4];
    const float* bb = (const float*)d_in[5];
    const int* u_idx = (const int*)d_in[6];
    const int* v_idx = (const int*)d_in[7];
    const int* uc = (const int*)d_in[8];
    const int* vc = (const int*)d_in[9];
    const int E = in_sizes[6];

    float* out = (float*)d_out;
    float* outXq = out;                 // NQ*DD
    float* outXt = out + NQ * DD;       // NT*DD

    char* ws = (char*)d_ws;
    float* Yqa = (float*)ws;                 ws += NQ * DD * sizeof(float);     // 512K
    float* Yqb = (float*)ws;                 ws += NQ * DD * sizeof(float);     // 512K
    int* cnt = (int*)ws;                     ws += NT * sizeof(int);            // 512K
    int* offs = (int*)ws;                    ws += NT * sizeof(int);            // 512K
    int* bsums = (int*)ws;                   ws += 4096;
    unsigned short* rank = (unsigned short*)ws; ws += (size_t)E * sizeof(unsigned short); // 4M
    int* u_sorted = (int*)ws;                ws += (size_t)E * sizeof(int);     // 8M

    // Output 0 is Xq unchanged.
    hipMemcpyAsync(outXq, Xq, NQ * DD * sizeof(float), hipMemcpyDeviceToDevice, stream);
    hipMemsetAsync(cnt, 0, NT * sizeof(int), stream);

    yq_kernel<<<NQ / 4, 256, 0, stream>>>(Xq, Wa, Wb, Yqa, Yqb);

    int eblk = (E + 255) / 256;
    hist_rank_kernel<<<eblk, 256, 0, stream>>>(v_idx, cnt, rank, E);
    scan1_kernel<<<NBLK, SCAN_BLK, 0, stream>>>(cnt, offs, bsums);
    scan2_kernel<<<1, NBLK, 0, stream>>>(bsums);
    scan3_kernel<<<NBLK, SCAN_BLK, 0, stream>>>(cnt, offs, bsums);
    scatter_u_kernel<<<eblk, 256, 0, stream>>>(u_idx, v_idx, rank, offs, u_sorted, E);

    row_score_agg_kernel<<<8192, 256, 0, stream>>>(Xq, Xt, Yqa, Yqb, ba, bb, offs, cnt,
                                                   u_sorted, outXt);
    consensus_kernel<<<(MM * DD) / 256, 256, 0, stream>>>(Xq, uc, vc, outXt);
}